// Round 1
// baseline (292.705 us; speedup 1.0000x reference)
//
#include <hip/hip_runtime.h>
#include <cstdint>
#include <cstddef>

#define N_ROWS 8192
#define DIM_IN 512
#define HID 64
#define MOT 64
#define INV_N2 (1.0f / (8192.0f * 8192.0f))

// ---------------------------------------------------------------------------
// Phase 1: M = relu(X @ W1 + b1) @ W2 + b2, plus row squared norms.
// Block = 256 threads (16x16), 64 rows per block.
// ---------------------------------------------------------------------------
__global__ __launch_bounds__(256) void functor_kernel(
    const float* __restrict__ X, const float* __restrict__ W1, const float* __restrict__ b1,
    const float* __restrict__ W2, const float* __restrict__ b2,
    float* __restrict__ Mout, float* __restrict__ norms)
{
    __shared__ float XsT[64][68];   // [k][row], padded stride 68 (16B aligned, 2-way banks)
    __shared__ float Ws[64][64];    // W chunk, natural [k][col]
    __shared__ float HsT[64][68];   // [h][row]

    const int t  = threadIdx.x;
    const int tx = t & 15;          // col group
    const int ty = t >> 4;          // row group
    const int row0 = blockIdx.x * 64;

    float c[4][4] = {};

    // ---- layer 1: K = 512 in 8 chunks of 64 ----
    for (int kc = 0; kc < DIM_IN; kc += 64) {
        #pragma unroll
        for (int q = 0; q < 4; ++q) {
            int idx = q * 256 + t;            // 0..1023
            int row = idx >> 4;               // 0..63
            int k4  = (idx & 15) << 2;        // 0..60
            float4 v = *(const float4*)&X[(size_t)(row0 + row) * DIM_IN + kc + k4];
            XsT[k4 + 0][row] = v.x;
            XsT[k4 + 1][row] = v.y;
            XsT[k4 + 2][row] = v.z;
            XsT[k4 + 3][row] = v.w;
            *(float4*)&Ws[row][k4] = *(const float4*)&W1[(size_t)(kc + row) * HID + k4];
        }
        __syncthreads();
        #pragma unroll 4
        for (int k = 0; k < 64; ++k) {
            float4 a = *(const float4*)&XsT[k][ty * 4];
            float4 b = *(const float4*)&Ws[k][tx * 4];
            float av[4] = {a.x, a.y, a.z, a.w};
            float bv[4] = {b.x, b.y, b.z, b.w};
            #pragma unroll
            for (int i = 0; i < 4; ++i)
                #pragma unroll
                for (int j = 0; j < 4; ++j)
                    c[i][j] = fmaf(av[i], bv[j], c[i][j]);
        }
        __syncthreads();
    }

    // ---- bias + relu -> HsT (transposed) ----
    #pragma unroll
    for (int i = 0; i < 4; ++i)
        #pragma unroll
        for (int j = 0; j < 4; ++j) {
            float h = c[i][j] + b1[tx * 4 + j];
            HsT[tx * 4 + j][ty * 4 + i] = fmaxf(h, 0.0f);
            c[i][j] = 0.0f;
        }

    // ---- stage W2 (reuse Ws; safe: synced after last chunk's reads) ----
    #pragma unroll
    for (int q = 0; q < 4; ++q) {
        int idx = q * 256 + t;
        int row = idx >> 4;
        int k4  = (idx & 15) << 2;
        *(float4*)&Ws[row][k4] = *(const float4*)&W2[(size_t)row * MOT + k4];
    }
    __syncthreads();

    // ---- layer 2: K = 64 ----
    #pragma unroll 4
    for (int k = 0; k < 64; ++k) {
        float4 a = *(const float4*)&HsT[k][ty * 4];
        float4 b = *(const float4*)&Ws[k][tx * 4];
        float av[4] = {a.x, a.y, a.z, a.w};
        float bv[4] = {b.x, b.y, b.z, b.w};
        #pragma unroll
        for (int i = 0; i < 4; ++i)
            #pragma unroll
            for (int j = 0; j < 4; ++j)
                c[i][j] = fmaf(av[i], bv[j], c[i][j]);
    }

    // ---- bias + write M (scalar stores: Mout is 4B-aligned only) + norms ----
    float p[4] = {0.0f, 0.0f, 0.0f, 0.0f};
    #pragma unroll
    for (int i = 0; i < 4; ++i)
        #pragma unroll
        for (int j = 0; j < 4; ++j) {
            float m = c[i][j] + b2[tx * 4 + j];
            Mout[(size_t)(row0 + ty * 4 + i) * MOT + tx * 4 + j] = m;
            p[i] = fmaf(m, m, p[i]);
        }
    #pragma unroll
    for (int off = 1; off < 16; off <<= 1)
        #pragma unroll
        for (int i = 0; i < 4; ++i)
            p[i] += __shfl_xor(p[i], off, 64);
    if (tx == 0) {
        #pragma unroll
        for (int i = 0; i < 4; ++i)
            norms[row0 + ty * 4 + i] = p[i];
    }
}

// ---------------------------------------------------------------------------
// Phase 2: pairwise exp(-0.5*d^2) sums. One block = one 128x128 tile.
// which 0: (A,A) lower-tri, 1: (B,B) lower-tri, 2: (A,B) full grid.
// Each block atomically adds its weighted partial into out0 (= &mmd).
// ---------------------------------------------------------------------------
__global__ __launch_bounds__(256) void pair_kernel(
    const float* __restrict__ Mbase, const float* __restrict__ nA,
    const float* __restrict__ nB, float* __restrict__ out0)
{
    const int T   = N_ROWS / 128;      // 64
    const int TRI = T * (T + 1) / 2;   // 2080

    int id = blockIdx.x;
    int which, bi, bj;
    if (id < 2 * TRI) {
        which = (id < TRI) ? 0 : 1;
        if (which) id -= TRI;
        int r = (int)((sqrtf(8.0f * (float)id + 1.0f) - 1.0f) * 0.5f);
        while ((r + 1) * (r + 2) / 2 <= id) ++r;
        while (r * (r + 1) / 2 > id) --r;
        bi = r;
        bj = id - r * (r + 1) / 2;     // bj <= bi
    } else {
        id -= 2 * TRI;
        which = 2;
        bi = id >> 6;
        bj = id & (T - 1);
    }

    const float* P  = Mbase + ((which == 1) ? (size_t)N_ROWS * MOT : 0);
    const float* Q  = Mbase + ((which == 0) ? 0 : (size_t)N_ROWS * MOT);
    const float* nP = (which == 1) ? nB : nA;
    const float* nQ = (which == 0) ? nA : nB;

    __shared__ float As[128][68];
    __shared__ float Bs[128][68];

    const int t  = threadIdx.x;
    const int tx = t & 15;
    const int ty = t >> 4;
    const int ar0 = bi * 128, br0 = bj * 128;

    // stage (scalar global loads: P/Q are 4B-aligned only; LDS writes vectorized)
    #pragma unroll
    for (int q = 0; q < 8; ++q) {
        int idx = q * 256 + t;        // 0..2047
        int row = idx >> 4;           // 0..127
        int k4  = (idx & 15) << 2;    // 0..60
        const float* pa = &P[(size_t)(ar0 + row) * MOT + k4];
        const float* pb = &Q[(size_t)(br0 + row) * MOT + k4];
        float4 va, vb;
        va.x = pa[0]; va.y = pa[1]; va.z = pa[2]; va.w = pa[3];
        vb.x = pb[0]; vb.y = pb[1]; vb.z = pb[2]; vb.w = pb[3];
        *(float4*)&As[row][k4] = va;
        *(float4*)&Bs[row][k4] = vb;
    }
    __syncthreads();

    // 8x8 micro-tile, rows r = ty + 16*i, cols c = tx + 16*j
    float acc[8][8] = {};
    #pragma unroll 2
    for (int k4 = 0; k4 < MOT; k4 += 4) {
        float4 a[8], b[8];
        #pragma unroll
        for (int i = 0; i < 8; ++i) a[i] = *(const float4*)&As[ty + 16 * i][k4];
        #pragma unroll
        for (int j = 0; j < 8; ++j) b[j] = *(const float4*)&Bs[tx + 16 * j][k4];
        #pragma unroll
        for (int i = 0; i < 8; ++i)
            #pragma unroll
            for (int j = 0; j < 8; ++j) {
                acc[i][j] = fmaf(a[i].x, b[j].x, acc[i][j]);
                acc[i][j] = fmaf(a[i].y, b[j].y, acc[i][j]);
                acc[i][j] = fmaf(a[i].z, b[j].z, acc[i][j]);
                acc[i][j] = fmaf(a[i].w, b[j].w, acc[i][j]);
            }
    }

    // epilogue: d = ||a||^2 + ||b||^2 - 2 a.b ; s += exp(-d/2)
    float aa[8], bb[8];
    #pragma unroll
    for (int i = 0; i < 8; ++i) aa[i] = nP[ar0 + ty + 16 * i];
    #pragma unroll
    for (int j = 0; j < 8; ++j) bb[j] = nQ[br0 + tx + 16 * j];

    float s = 0.0f;
    #pragma unroll
    for (int i = 0; i < 8; ++i)
        #pragma unroll
        for (int j = 0; j < 8; ++j) {
            float d = fmaxf(aa[i] + bb[j] - 2.0f * acc[i][j], 0.0f);
            s += __expf(-0.5f * d);
        }

    // weight: symmetric off-diagonal tiles count twice; xy tiles weighted -2
    float scale = (which == 2) ? (-2.0f * INV_N2)
                               : ((bi != bj) ? (2.0f * INV_N2) : INV_N2);
    s *= scale;

    #pragma unroll
    for (int off = 32; off > 0; off >>= 1) s += __shfl_xor(s, off, 64);

    __shared__ float red[4];
    if ((t & 63) == 0) red[t >> 6] = s;
    __syncthreads();
    if (t == 0) atomicAdd(out0, red[0] + red[1] + red[2] + red[3]);
}

// ---------------------------------------------------------------------------
extern "C" void kernel_launch(void* const* d_in, const int* in_sizes, int n_in,
                              void* d_out, int out_size, void* d_ws, size_t ws_size,
                              hipStream_t stream)
{
    const float* XA  = (const float*)d_in[0];
    const float* XB  = (const float*)d_in[1];
    const float* WA1 = (const float*)d_in[2];
    const float* bA1 = (const float*)d_in[3];
    const float* WA2 = (const float*)d_in[4];
    const float* bA2 = (const float*)d_in[5];
    const float* WB1 = (const float*)d_in[6];
    const float* bB1 = (const float*)d_in[7];
    const float* WB2 = (const float*)d_in[8];
    const float* bB2 = (const float*)d_in[9];

    float* out = (float*)d_out;
    float* MA  = out + 1;
    float* MB  = out + 1 + (size_t)N_ROWS * MOT;
    float* nA  = (float*)d_ws;          // 8192 floats
    float* nB  = nA + N_ROWS;           // 8192 floats  (needs 64 KiB of ws)

    functor_kernel<<<N_ROWS / 64, 256, 0, stream>>>(XA, WA1, bA1, WA2, bA2, MA, nA);
    functor_kernel<<<N_ROWS / 64, 256, 0, stream>>>(XB, WB1, bB1, WB2, bB2, MB, nB);

    hipMemsetAsync(d_out, 0, sizeof(float), stream);  // zero mmd accumulator

    const int T = N_ROWS / 128, TRI = T * (T + 1) / 2;
    pair_kernel<<<2 * TRI + T * T, 256, 0, stream>>>(MA, nA, nB, out);
}

// Round 2
// 178.128 us; speedup vs baseline: 1.6432x; 1.6432x over previous
//
#include <hip/hip_runtime.h>
#include <hip/hip_bf16.h>
#include <cstdint>
#include <cstddef>

#define N_ROWS 8192
#define DIM_IN 512
#define HID 64
#define MOT 64
#define INV_N2 (1.0f / (8192.0f * 8192.0f))

typedef __attribute__((ext_vector_type(8))) short bf16x8;
typedef __attribute__((ext_vector_type(4))) float f32x4;

__device__ inline unsigned short f2bf(float f) {
    union { __hip_bfloat16 h; unsigned short u; } cv;
    cv.h = __float2bfloat16(f);   // RNE
    return cv.u;
}
__device__ inline float bfbits2f(unsigned short u) {
    union { unsigned int i; float f; } cv;
    cv.i = ((unsigned int)u) << 16;
    return cv.f;
}
__device__ inline void gl_lds16(const void* g, void* l) {
    __builtin_amdgcn_global_load_lds(
        (const __attribute__((address_space(1))) unsigned int*)g,
        (__attribute__((address_space(3))) unsigned int*)l, 16, 0, 0);
}

// ---------------------------------------------------------------------------
// Phase 1: M = relu(X @ W1 + b1) @ W2 + b2, fp32 exact. Also emits:
//  - norms[row]  = ||bf16(M_row)||^2  (fp32; from rounded values when Pbf)
//  - Pbf         = bf16(M) stored pre-swizzled per 128-row tile:
//                  byte addr = tile*16384 + r*128 + ((col*2) ^ ((r&7)<<4))
// Block = 256 threads (16x16), 64 rows per block.
// ---------------------------------------------------------------------------
__global__ __launch_bounds__(256) void functor_kernel(
    const float* __restrict__ X, const float* __restrict__ W1, const float* __restrict__ b1,
    const float* __restrict__ W2, const float* __restrict__ b2,
    float* __restrict__ Mout, float* __restrict__ norms,
    unsigned short* __restrict__ Pbf)
{
    __shared__ float XsT[64][68];
    __shared__ float Ws[64][64];
    __shared__ float HsT[64][68];

    const int t  = threadIdx.x;
    const int tx = t & 15;
    const int ty = t >> 4;
    const int row0 = blockIdx.x * 64;

    float c[4][4] = {};

    // ---- layer 1: K = 512 in 8 chunks of 64 ----
    for (int kc = 0; kc < DIM_IN; kc += 64) {
        #pragma unroll
        for (int q = 0; q < 4; ++q) {
            int idx = q * 256 + t;
            int row = idx >> 4;
            int k4  = (idx & 15) << 2;
            float4 v = *(const float4*)&X[(size_t)(row0 + row) * DIM_IN + kc + k4];
            XsT[k4 + 0][row] = v.x;
            XsT[k4 + 1][row] = v.y;
            XsT[k4 + 2][row] = v.z;
            XsT[k4 + 3][row] = v.w;
            *(float4*)&Ws[row][k4] = *(const float4*)&W1[(size_t)(kc + row) * HID + k4];
        }
        __syncthreads();
        #pragma unroll 4
        for (int k = 0; k < 64; ++k) {
            float4 a = *(const float4*)&XsT[k][ty * 4];
            float4 b = *(const float4*)&Ws[k][tx * 4];
            float av[4] = {a.x, a.y, a.z, a.w};
            float bv[4] = {b.x, b.y, b.z, b.w};
            #pragma unroll
            for (int i = 0; i < 4; ++i)
                #pragma unroll
                for (int j = 0; j < 4; ++j)
                    c[i][j] = fmaf(av[i], bv[j], c[i][j]);
        }
        __syncthreads();
    }

    // ---- bias + relu -> HsT ----
    #pragma unroll
    for (int i = 0; i < 4; ++i)
        #pragma unroll
        for (int j = 0; j < 4; ++j) {
            float h = c[i][j] + b1[tx * 4 + j];
            HsT[tx * 4 + j][ty * 4 + i] = fmaxf(h, 0.0f);
            c[i][j] = 0.0f;
        }

    #pragma unroll
    for (int q = 0; q < 4; ++q) {
        int idx = q * 256 + t;
        int row = idx >> 4;
        int k4  = (idx & 15) << 2;
        *(float4*)&Ws[row][k4] = *(const float4*)&W2[(size_t)row * MOT + k4];
    }
    __syncthreads();

    // ---- layer 2: K = 64 ----
    #pragma unroll 4
    for (int k = 0; k < 64; ++k) {
        float4 a = *(const float4*)&HsT[k][ty * 4];
        float4 b = *(const float4*)&Ws[k][tx * 4];
        float av[4] = {a.x, a.y, a.z, a.w};
        float bv[4] = {b.x, b.y, b.z, b.w};
        #pragma unroll
        for (int i = 0; i < 4; ++i)
            #pragma unroll
            for (int j = 0; j < 4; ++j)
                c[i][j] = fmaf(av[i], bv[j], c[i][j]);
    }

    // ---- bias + write M + bf16 swizzled copy + norms ----
    float p[4] = {0.0f, 0.0f, 0.0f, 0.0f};
    #pragma unroll
    for (int i = 0; i < 4; ++i) {
        unsigned short q[4];
        #pragma unroll
        for (int j = 0; j < 4; ++j) {
            float m = c[i][j] + b2[tx * 4 + j];
            Mout[(size_t)(row0 + ty * 4 + i) * MOT + tx * 4 + j] = m;
            float mn = m;
            if (Pbf) { q[j] = f2bf(m); mn = bfbits2f(q[j]); }
            p[i] = fmaf(mn, mn, p[i]);
        }
        if (Pbf) {
            int grow = row0 + ty * 4 + i;
            int r    = grow & 127;
            size_t tile = (size_t)(grow >> 7);
            int swz  = (tx * 8) ^ ((r & 7) << 4);
            ushort4 v; v.x = q[0]; v.y = q[1]; v.z = q[2]; v.w = q[3];
            *(ushort4*)((char*)Pbf + tile * 16384 + (size_t)r * 128 + swz) = v;
        }
    }
    #pragma unroll
    for (int off = 1; off < 16; off <<= 1)
        #pragma unroll
        for (int i = 0; i < 4; ++i)
            p[i] += __shfl_xor(p[i], off, 64);
    if (tx == 0) {
        #pragma unroll
        for (int i = 0; i < 4; ++i)
            norms[row0 + ty * 4 + i] = p[i];
    }
}

// ---------------------------------------------------------------------------
// Tile-index decode shared by pair kernels.
// ---------------------------------------------------------------------------
__device__ inline void decode_tile(int id, int T, int TRI, int& which, int& bi, int& bj) {
    if (id < 2 * TRI) {
        which = (id < TRI) ? 0 : 1;
        if (which) id -= TRI;
        int r = (int)((sqrtf(8.0f * (float)id + 1.0f) - 1.0f) * 0.5f);
        while ((r + 1) * (r + 2) / 2 <= id) ++r;
        while (r * (r + 1) / 2 > id) --r;
        bi = r;
        bj = id - r * (r + 1) / 2;
    } else {
        id -= 2 * TRI;
        which = 2;
        bi = id >> 6;
        bj = id & (T - 1);
    }
}

// ---------------------------------------------------------------------------
// Phase 2 (MFMA): one block = one 128x128 tile. 4 waves, each owns a 64x64
// sub-tile as 4x4 fragments of mfma_f32_16x16x32_bf16 over K=64.
// Tiles are contiguous 16KB pre-swizzled chunks -> linear global_load_lds.
// ---------------------------------------------------------------------------
__global__ __launch_bounds__(256) void pair_mfma_kernel(
    const unsigned short* __restrict__ PA, const unsigned short* __restrict__ PB,
    const float* __restrict__ nA, const float* __restrict__ nB,
    float* __restrict__ out0)
{
    const int T   = N_ROWS / 128;
    const int TRI = T * (T + 1) / 2;

    int which, bi, bj;
    decode_tile(blockIdx.x, T, TRI, which, bi, bj);

    const unsigned short* P = (which == 1) ? PB : PA;
    const unsigned short* Q = (which == 0) ? PA : PB;
    const float* nP = (which == 1) ? nB : nA;
    const float* nQ = (which == 0) ? nA : nB;

    __shared__ unsigned short As[8192];   // 16KB, swizzled layout
    __shared__ unsigned short Bs[8192];
    __shared__ float nAs[128], nBs[128];
    __shared__ float red[4];

    const int t    = threadIdx.x;
    const int lane = t & 63;
    const int wave = t >> 6;
    const int wr   = wave >> 1, wc = wave & 1;

    // stage: each wave copies its 1KB slice per pass; lane*16 added by HW on LDS side
    {
        const char* srcA = (const char*)P + (size_t)bi * 16384 + wave * 1024 + lane * 16;
        const char* srcB = (const char*)Q + (size_t)bj * 16384 + wave * 1024 + lane * 16;
        char* ldsA = (char*)As + wave * 1024;
        char* ldsB = (char*)Bs + wave * 1024;
        #pragma unroll
        for (int p4 = 0; p4 < 4; ++p4) {
            gl_lds16(srcA + p4 * 4096, ldsA + p4 * 4096);
            gl_lds16(srcB + p4 * 4096, ldsB + p4 * 4096);
        }
    }
    if (t < 128) nAs[t] = nP[bi * 128 + t];
    else         nBs[t - 128] = nQ[bj * 128 + (t - 128)];
    __syncthreads();

    // fragment addressing (swizzle: byte ^ ((row&7)<<4); row&7 == lane&7 here)
    const int sw = (lane & 7) << 4;
    const int kb = (lane >> 4) << 4;      // (lane>>4)*16 bytes = 8 bf16 k-chunk

    f32x4 acc[4][4] = {};
    #pragma unroll
    for (int k0 = 0; k0 < 2; ++k0) {      // K halves of 32
        const int koff = (k0 * 64 + kb) ^ sw;
        bf16x8 af[4], bf[4];
        #pragma unroll
        for (int i = 0; i < 4; ++i)
            af[i] = *(const bf16x8*)((const char*)As + (wr * 64 + i * 16 + (lane & 15)) * 128 + koff);
        #pragma unroll
        for (int j = 0; j < 4; ++j)
            bf[j] = *(const bf16x8*)((const char*)Bs + (wc * 64 + j * 16 + (lane & 15)) * 128 + koff);
        #pragma unroll
        for (int i = 0; i < 4; ++i)
            #pragma unroll
            for (int j = 0; j < 4; ++j)
                acc[i][j] = __builtin_amdgcn_mfma_f32_16x16x32_bf16(af[i], bf[j], acc[i][j], 0, 0, 0);
    }

    // epilogue: exp(min(dot - (na+nb)/2, 0)) == exp(-max(d,0)/2)
    float aa2[16], bb2[4];
    #pragma unroll
    for (int i = 0; i < 4; ++i)
        #pragma unroll
        for (int r = 0; r < 4; ++r)
            aa2[i * 4 + r] = 0.5f * nAs[wr * 64 + i * 16 + ((lane >> 4) << 2) + r];
    #pragma unroll
    for (int j = 0; j < 4; ++j)
        bb2[j] = 0.5f * nBs[wc * 64 + j * 16 + (lane & 15)];

    float s = 0.0f;
    #pragma unroll
    for (int i = 0; i < 4; ++i)
        #pragma unroll
        for (int j = 0; j < 4; ++j)
            #pragma unroll
            for (int r = 0; r < 4; ++r) {
                float tv = acc[i][j][r] - aa2[i * 4 + r] - bb2[j];
                s += __expf(fminf(tv, 0.0f));
            }

    float scale = (which == 2) ? (-2.0f * INV_N2)
                               : ((bi != bj) ? (2.0f * INV_N2) : INV_N2);
    s *= scale;

    #pragma unroll
    for (int off = 32; off > 0; off >>= 1) s += __shfl_xor(s, off, 64);
    if ((t & 63) == 0) red[t >> 6] = s;
    __syncthreads();
    if (t == 0) atomicAdd(out0, red[0] + red[1] + red[2] + red[3]);
}

// ---------------------------------------------------------------------------
// Fallback fp32 pair kernel (used only if workspace is too small for bf16 M).
// ---------------------------------------------------------------------------
__global__ __launch_bounds__(256) void pair_kernel_f32(
    const float* __restrict__ Mbase, const float* __restrict__ nA,
    const float* __restrict__ nB, float* __restrict__ out0)
{
    const int T   = N_ROWS / 128;
    const int TRI = T * (T + 1) / 2;

    int which, bi, bj;
    decode_tile(blockIdx.x, T, TRI, which, bi, bj);

    const float* P  = Mbase + ((which == 1) ? (size_t)N_ROWS * MOT : 0);
    const float* Q  = Mbase + ((which == 0) ? 0 : (size_t)N_ROWS * MOT);
    const float* nP = (which == 1) ? nB : nA;
    const float* nQ = (which == 0) ? nA : nB;

    __shared__ float As[128][68];
    __shared__ float Bs[128][68];

    const int t  = threadIdx.x;
    const int tx = t & 15;
    const int ty = t >> 4;
    const int ar0 = bi * 128, br0 = bj * 128;

    #pragma unroll
    for (int q = 0; q < 8; ++q) {
        int idx = q * 256 + t;
        int row = idx >> 4;
        int k4  = (idx & 15) << 2;
        const float* pa = &P[(size_t)(ar0 + row) * MOT + k4];
        const float* pb = &Q[(size_t)(br0 + row) * MOT + k4];
        float4 va, vb;
        va.x = pa[0]; va.y = pa[1]; va.z = pa[2]; va.w = pa[3];
        vb.x = pb[0]; vb.y = pb[1]; vb.z = pb[2]; vb.w = pb[3];
        *(float4*)&As[row][k4] = va;
        *(float4*)&Bs[row][k4] = vb;
    }
    __syncthreads();

    float acc[8][8] = {};
    #pragma unroll 2
    for (int k4 = 0; k4 < MOT; k4 += 4) {
        float4 a[8], b[8];
        #pragma unroll
        for (int i = 0; i < 8; ++i) a[i] = *(const float4*)&As[ty + 16 * i][k4];
        #pragma unroll
        for (int j = 0; j < 8; ++j) b[j] = *(const float4*)&Bs[tx + 16 * j][k4];
        #pragma unroll
        for (int i = 0; i < 8; ++i)
            #pragma unroll
            for (int j = 0; j < 8; ++j) {
                acc[i][j] = fmaf(a[i].x, b[j].x, acc[i][j]);
                acc[i][j] = fmaf(a[i].y, b[j].y, acc[i][j]);
                acc[i][j] = fmaf(a[i].z, b[j].z, acc[i][j]);
                acc[i][j] = fmaf(a[i].w, b[j].w, acc[i][j]);
            }
    }

    float aa[8], bb[8];
    #pragma unroll
    for (int i = 0; i < 8; ++i) aa[i] = nP[ar0 + ty + 16 * i];
    #pragma unroll
    for (int j = 0; j < 8; ++j) bb[j] = nQ[br0 + tx + 16 * j];

    float s = 0.0f;
    #pragma unroll
    for (int i = 0; i < 8; ++i)
        #pragma unroll
        for (int j = 0; j < 8; ++j) {
            float d = fmaxf(aa[i] + bb[j] - 2.0f * acc[i][j], 0.0f);
            s += __expf(-0.5f * d);
        }

    float scale = (which == 2) ? (-2.0f * INV_N2)
                               : ((bi != bj) ? (2.0f * INV_N2) : INV_N2);
    s *= scale;

    #pragma unroll
    for (int off = 32; off > 0; off >>= 1) s += __shfl_xor(s, off, 64);

    __shared__ float red[4];
    if ((t & 63) == 0) red[t >> 6] = s;
    __syncthreads();
    if (t == 0) atomicAdd(out0, red[0] + red[1] + red[2] + red[3]);
}

// ---------------------------------------------------------------------------
extern "C" void kernel_launch(void* const* d_in, const int* in_sizes, int n_in,
                              void* d_out, int out_size, void* d_ws, size_t ws_size,
                              hipStream_t stream)
{
    const float* XA  = (const float*)d_in[0];
    const float* XB  = (const float*)d_in[1];
    const float* WA1 = (const float*)d_in[2];
    const float* bA1 = (const float*)d_in[3];
    const float* WA2 = (const float*)d_in[4];
    const float* bA2 = (const float*)d_in[5];
    const float* WB1 = (const float*)d_in[6];
    const float* bB1 = (const float*)d_in[7];
    const float* WB2 = (const float*)d_in[8];
    const float* bB2 = (const float*)d_in[9];

    float* out = (float*)d_out;
    float* MA  = out + 1;
    float* MB  = out + 1 + (size_t)N_ROWS * MOT;
    float* nA  = (float*)d_ws;
    float* nB  = nA + N_ROWS;

    const size_t need = 2 * (size_t)N_ROWS * sizeof(float)
                      + 2 * (size_t)N_ROWS * MOT * sizeof(unsigned short);
    const bool use_mfma = (ws_size >= need);

    unsigned short* PA = use_mfma ? (unsigned short*)(nB + N_ROWS) : nullptr;
    unsigned short* PB = use_mfma ? PA + (size_t)N_ROWS * MOT : nullptr;

    hipMemsetAsync(d_out, 0, sizeof(float), stream);  // zero mmd accumulator

    functor_kernel<<<N_ROWS / 64, 256, 0, stream>>>(XA, WA1, bA1, WA2, bA2, MA, nA, PA);
    functor_kernel<<<N_ROWS / 64, 256, 0, stream>>>(XB, WB1, bB1, WB2, bB2, MB, nB, PB);

    const int T = N_ROWS / 128, TRI = T * (T + 1) / 2;
    const int n_tiles = 2 * TRI + T * T;
    if (use_mfma)
        pair_mfma_kernel<<<n_tiles, 256, 0, stream>>>(PA, PB, nA, nB, out);
    else
        pair_kernel_f32<<<n_tiles, 256, 0, stream>>>(MA, nA, nB, out);
}

// Round 3
// 78.890 us; speedup vs baseline: 3.7103x; 2.2579x over previous
//
#include <hip/hip_runtime.h>
#include <hip/hip_bf16.h>
#include <cstdint>
#include <cstddef>

#define N_ROWS 8192
#define DIM_IN 512
#define MOT 64
#define INV_N2 (1.0f / (8192.0f * 8192.0f))
#define PAIR_GRID 512

typedef __attribute__((ext_vector_type(8))) short bf16x8;
typedef __attribute__((ext_vector_type(4))) float f32x4;

__device__ inline unsigned short f2bf(float f) {
    union { __hip_bfloat16 h; unsigned short u; } cv;
    cv.h = __float2bfloat16(f);   // RNE
    return cv.u;
}
__device__ inline float bfbits2f(unsigned short u) {
    union { unsigned int i; float f; } cv;
    cv.i = ((unsigned int)u) << 16;
    return cv.f;
}
__device__ inline void gl_lds16(const void* g, void* l) {
    __builtin_amdgcn_global_load_lds(
        (const __attribute__((address_space(1))) unsigned int*)g,
        (__attribute__((address_space(3))) unsigned int*)l, 16, 0, 0);
}
__device__ inline void gl_lds4(const void* g, void* l) {
    __builtin_amdgcn_global_load_lds(
        (const __attribute__((address_space(1))) unsigned int*)g,
        (__attribute__((address_space(3))) unsigned int*)l, 4, 0, 0);
}

// ---------------------------------------------------------------------------
// Phase 1 (fused A+B): M = relu(X @ W1 + b1) @ W2 + b2, fp32 exact.
// 512 blocks x 256 threads; 32 rows/block; blockIdx>>8 selects input set.
// Emits Mout (fp32 exact), norms = ||bf16(M_row)||^2, and Pbf = bf16(M)
// pre-swizzled per 128-row tile: byte = tile*16384 + r*128 + ((col*2)^((r&7)<<4))
// ---------------------------------------------------------------------------
__global__ __launch_bounds__(256) void functor2_kernel(
    const float* __restrict__ XA, const float* __restrict__ WA1, const float* __restrict__ bA1,
    const float* __restrict__ WA2, const float* __restrict__ bA2,
    const float* __restrict__ XB, const float* __restrict__ WB1, const float* __restrict__ bB1,
    const float* __restrict__ WB2, const float* __restrict__ bB2,
    float* __restrict__ MA, float* __restrict__ MB,
    float* __restrict__ nAo, float* __restrict__ nBo,
    unsigned short* __restrict__ PbfA, unsigned short* __restrict__ PbfB)
{
    const int half = blockIdx.x >> 8;          // 0: A path, 1: B path
    const float* X  = half ? XB  : XA;
    const float* W1 = half ? WB1 : WA1;
    const float* b1 = half ? bB1 : bA1;
    const float* W2 = half ? WB2 : WA2;
    const float* b2 = half ? bB2 : bA2;
    float* Mout  = half ? MB  : MA;
    float* norms = half ? nBo : nAo;
    unsigned short* Pbf = half ? PbfB : PbfA;

    __shared__ float XsT[64][34];   // [k][row], stride 34 (8B-aligned float2 reads)
    __shared__ float Ws[64][64];
    __shared__ float HsT[64][34];

    const int t  = threadIdx.x;
    const int tx = t & 15;
    const int ty = t >> 4;
    const int row0 = (blockIdx.x & 255) * 32;

    float c[2][4] = {};

    // ---- layer 1: K = 512 in 8 chunks of 64 ----
    for (int kc = 0; kc < DIM_IN; kc += 64) {
        #pragma unroll
        for (int q = 0; q < 2; ++q) {           // X: 32x64 floats
            int idx = q * 256 + t;              // 0..511
            int row = idx >> 4;                 // 0..31
            int k4  = (idx & 15) << 2;          // 0..60
            float4 v = *(const float4*)&X[(size_t)(row0 + row) * DIM_IN + kc + k4];
            XsT[k4 + 0][row] = v.x;
            XsT[k4 + 1][row] = v.y;
            XsT[k4 + 2][row] = v.z;
            XsT[k4 + 3][row] = v.w;
        }
        #pragma unroll
        for (int q = 0; q < 4; ++q) {           // W1 chunk: 64x64
            int idx = q * 256 + t;
            int row = idx >> 4;                 // 0..63
            int k4  = (idx & 15) << 2;
            *(float4*)&Ws[row][k4] = *(const float4*)&W1[(size_t)(kc + row) * MOT + k4];
        }
        __syncthreads();
        #pragma unroll 8
        for (int k = 0; k < 64; ++k) {
            float2 a = *(const float2*)&XsT[k][ty * 2];
            float4 b = *(const float4*)&Ws[k][tx * 4];
            float av[2] = {a.x, a.y};
            float bv[4] = {b.x, b.y, b.z, b.w};
            #pragma unroll
            for (int i = 0; i < 2; ++i)
                #pragma unroll
                for (int j = 0; j < 4; ++j)
                    c[i][j] = fmaf(av[i], bv[j], c[i][j]);
        }
        __syncthreads();
    }

    // ---- bias + relu -> HsT (transposed) ----
    {
        float bias1[4];
        #pragma unroll
        for (int j = 0; j < 4; ++j) bias1[j] = b1[tx * 4 + j];
        #pragma unroll
        for (int i = 0; i < 2; ++i)
            #pragma unroll
            for (int j = 0; j < 4; ++j) {
                float h = c[i][j] + bias1[j];
                HsT[tx * 4 + j][ty * 2 + i] = fmaxf(h, 0.0f);
                c[i][j] = 0.0f;
            }
    }

    // ---- stage W2 ----
    #pragma unroll
    for (int q = 0; q < 4; ++q) {
        int idx = q * 256 + t;
        int row = idx >> 4;
        int k4  = (idx & 15) << 2;
        *(float4*)&Ws[row][k4] = *(const float4*)&W2[(size_t)row * MOT + k4];
    }
    __syncthreads();

    // ---- layer 2: K = 64 ----
    #pragma unroll 8
    for (int k = 0; k < 64; ++k) {
        float2 a = *(const float2*)&HsT[k][ty * 2];
        float4 b = *(const float4*)&Ws[k][tx * 4];
        float av[2] = {a.x, a.y};
        float bv[4] = {b.x, b.y, b.z, b.w};
        #pragma unroll
        for (int i = 0; i < 2; ++i)
            #pragma unroll
            for (int j = 0; j < 4; ++j)
                c[i][j] = fmaf(av[i], bv[j], c[i][j]);
    }

    // ---- bias + write M + bf16 swizzled copy + norms ----
    float bias2[4];
    #pragma unroll
    for (int j = 0; j < 4; ++j) bias2[j] = b2[tx * 4 + j];

    float p[2] = {0.0f, 0.0f};
    #pragma unroll
    for (int i = 0; i < 2; ++i) {
        unsigned short q4[4];
        int grow = row0 + ty * 2 + i;
        #pragma unroll
        for (int j = 0; j < 4; ++j) {
            float m = c[i][j] + bias2[j];
            Mout[(size_t)grow * MOT + tx * 4 + j] = m;
            q4[j] = f2bf(m);
            float mn = bfbits2f(q4[j]);
            p[i] = fmaf(mn, mn, p[i]);
        }
        int r = grow & 127;
        size_t tile = (size_t)(grow >> 7);
        int swz = (tx * 8) ^ ((r & 7) << 4);
        ushort4 v; v.x = q4[0]; v.y = q4[1]; v.z = q4[2]; v.w = q4[3];
        *(ushort4*)((char*)Pbf + tile * 16384 + (size_t)r * 128 + swz) = v;
    }
    #pragma unroll
    for (int off = 1; off < 16; off <<= 1)
        #pragma unroll
        for (int i = 0; i < 2; ++i)
            p[i] += __shfl_xor(p[i], off, 64);
    if (tx == 0) {
        norms[row0 + ty * 2 + 0] = p[0];
        norms[row0 + ty * 2 + 1] = p[1];
    }
}

// ---------------------------------------------------------------------------
__device__ inline void decode_tile(int id, int T, int TRI, int& which, int& bi, int& bj) {
    if (id < 2 * TRI) {
        which = (id < TRI) ? 0 : 1;
        if (which) id -= TRI;
        int r = (int)((sqrtf(8.0f * (float)id + 1.0f) - 1.0f) * 0.5f);
        while ((r + 1) * (r + 2) / 2 <= id) ++r;
        while (r * (r + 1) / 2 > id) --r;
        bi = r;
        bj = id - r * (r + 1) / 2;
    } else {
        id -= 2 * TRI;
        which = 2;
        bi = id >> 6;
        bj = id & (T - 1);
    }
}

// ---------------------------------------------------------------------------
// Phase 2: persistent MFMA pair kernel. 512 blocks loop over 8256 tiles with
// double-buffered LDS; prefetch tile t+1 via global_load_lds while computing
// tile t. Per-thread accumulator across tiles; one atomic per block.
// ---------------------------------------------------------------------------
__global__ __launch_bounds__(256) void pair_persist_kernel(
    const unsigned short* __restrict__ PA, const unsigned short* __restrict__ PB,
    const float* __restrict__ nA, const float* __restrict__ nB,
    float* __restrict__ out0)
{
    const int T   = N_ROWS / 128;      // 64
    const int TRI = T * (T + 1) / 2;   // 2080
    const int NT  = 2 * TRI + T * T;   // 8256

    __shared__ unsigned short As[2][8192];   // 2 x 16KB swizzled tiles
    __shared__ unsigned short Bs[2][8192];
    __shared__ float nAsh[2][128];
    __shared__ float nBsh[2][128];
    __shared__ float red[4];

    const int t    = threadIdx.x;
    const int lane = t & 63;
    const int wave = t >> 6;
    const int wr   = wave >> 1, wc = wave & 1;

    auto stage = [&](int nb, int swhich, int sbi, int sbj) {
        const unsigned short* P = (swhich == 1) ? PB : PA;
        const unsigned short* Q = (swhich == 0) ? PA : PB;
        const char* srcA = (const char*)P + (size_t)sbi * 16384 + wave * 1024 + lane * 16;
        const char* srcB = (const char*)Q + (size_t)sbj * 16384 + wave * 1024 + lane * 16;
        char* ldsA = (char*)&As[nb][0] + wave * 1024;
        char* ldsB = (char*)&Bs[nb][0] + wave * 1024;
        #pragma unroll
        for (int p4 = 0; p4 < 4; ++p4) {
            gl_lds16(srcA + p4 * 4096, ldsA + p4 * 4096);
            gl_lds16(srcB + p4 * 4096, ldsB + p4 * 4096);
        }
        const float* nP = (swhich == 1) ? nB : nA;
        const float* nQ = (swhich == 0) ? nA : nB;
        if (wave == 0) {
            gl_lds4(&nP[sbi * 128 + lane], &nAsh[nb][0]);
            gl_lds4(&nP[sbi * 128 + 64 + lane], &nAsh[nb][64]);
        }
        if (wave == 1) {
            gl_lds4(&nQ[sbj * 128 + lane], &nBsh[nb][0]);
            gl_lds4(&nQ[sbj * 128 + 64 + lane], &nBsh[nb][64]);
        }
    };

    int tid = blockIdx.x;
    int which, bi, bj;
    decode_tile(tid, T, TRI, which, bi, bj);
    stage(0, which, bi, bj);

    const int sw = (lane & 7) << 4;
    const int kb = (lane >> 4) << 4;

    float s_acc = 0.0f;
    int it = 0;
    while (true) {
        const int cur = it & 1;
        const int cwhich = which, cbi = bi, cbj = bj;

        __syncthreads();                         // buf[cur] staged & visible

        const int ntid = tid + PAIR_GRID;
        if (ntid < NT) {
            decode_tile(ntid, T, TRI, which, bi, bj);
            stage(cur ^ 1, which, bi, bj);       // prefetch; drained at next sync
        }

        // ---- MFMA on buf[cur] ----
        const char* Ab = (const char*)&As[cur][0];
        const char* Bb = (const char*)&Bs[cur][0];
        f32x4 acc[4][4] = {};
        #pragma unroll
        for (int k0 = 0; k0 < 2; ++k0) {
            const int koff = (k0 * 64 + kb) ^ sw;
            bf16x8 af[4], bf[4];
            #pragma unroll
            for (int i = 0; i < 4; ++i)
                af[i] = *(const bf16x8*)(Ab + (wr * 64 + i * 16 + (lane & 15)) * 128 + koff);
            #pragma unroll
            for (int j = 0; j < 4; ++j)
                bf[j] = *(const bf16x8*)(Bb + (wc * 64 + j * 16 + (lane & 15)) * 128 + koff);
            #pragma unroll
            for (int i = 0; i < 4; ++i)
                #pragma unroll
                for (int j = 0; j < 4; ++j)
                    acc[i][j] = __builtin_amdgcn_mfma_f32_16x16x32_bf16(af[i], bf[j], acc[i][j], 0, 0, 0);
        }

        // ---- epilogue: exp(dot - 0.5(na+nb)) summed ----
        float cAn[4][4], cBn[4];
        #pragma unroll
        for (int i = 0; i < 4; ++i) {
            float4 n4 = *(const float4*)&nAsh[cur][wr * 64 + i * 16 + ((lane >> 4) << 2)];
            cAn[i][0] = 0.5f * n4.x; cAn[i][1] = 0.5f * n4.y;
            cAn[i][2] = 0.5f * n4.z; cAn[i][3] = 0.5f * n4.w;
        }
        #pragma unroll
        for (int j = 0; j < 4; ++j)
            cBn[j] = 0.5f * nBsh[cur][wc * 64 + j * 16 + (lane & 15)];

        float stile = 0.0f;
        if (cwhich != 2 && cbi == cbj) {         // diagonal tile: clamp (exact d=0 diag)
            #pragma unroll
            for (int i = 0; i < 4; ++i)
                #pragma unroll
                for (int j = 0; j < 4; ++j)
                    #pragma unroll
                    for (int r = 0; r < 4; ++r) {
                        float tv = acc[i][j][r] - cAn[i][r] - cBn[j];
                        stile += __expf(fminf(tv, 0.0f));
                    }
        } else {
            #pragma unroll
            for (int i = 0; i < 4; ++i)
                #pragma unroll
                for (int j = 0; j < 4; ++j)
                    #pragma unroll
                    for (int r = 0; r < 4; ++r) {
                        float tv = acc[i][j][r] - cAn[i][r] - cBn[j];
                        stile += __expf(tv);
                    }
        }

        float scale = (cwhich == 2) ? (-2.0f * INV_N2)
                                    : ((cbi != cbj) ? (2.0f * INV_N2) : INV_N2);
        s_acc = fmaf(scale, stile, s_acc);

        if (ntid >= NT) break;
        tid = ntid; ++it;
    }

    #pragma unroll
    for (int off = 32; off > 0; off >>= 1) s_acc += __shfl_xor(s_acc, off, 64);
    if (lane == 0) red[wave] = s_acc;
    __syncthreads();
    if (t == 0) atomicAdd(out0, red[0] + red[1] + red[2] + red[3]);
}

// ---------------------------------------------------------------------------
extern "C" void kernel_launch(void* const* d_in, const int* in_sizes, int n_in,
                              void* d_out, int out_size, void* d_ws, size_t ws_size,
                              hipStream_t stream)
{
    const float* XA  = (const float*)d_in[0];
    const float* XB  = (const float*)d_in[1];
    const float* WA1 = (const float*)d_in[2];
    const float* bA1 = (const float*)d_in[3];
    const float* WA2 = (const float*)d_in[4];
    const float* bA2 = (const float*)d_in[5];
    const float* WB1 = (const float*)d_in[6];
    const float* bB1 = (const float*)d_in[7];
    const float* WB2 = (const float*)d_in[8];
    const float* bB2 = (const float*)d_in[9];

    float* out = (float*)d_out;
    float* MA  = out + 1;
    float* MB  = out + 1 + (size_t)N_ROWS * MOT;
    float* nA  = (float*)d_ws;                          // 8192 f32
    float* nB  = nA + N_ROWS;                           // 8192 f32
    unsigned short* PA = (unsigned short*)(nB + N_ROWS); // 8192x64 bf16 (swizzled)
    unsigned short* PB = PA + (size_t)N_ROWS * MOT;

    hipMemsetAsync(d_out, 0, sizeof(float), stream);    // zero mmd accumulator

    functor2_kernel<<<512, 256, 0, stream>>>(XA, WA1, bA1, WA2, bA2,
                                             XB, WB1, bB1, WB2, bB2,
                                             MA, MB, nA, nB, PA, PB);

    pair_persist_kernel<<<PAIR_GRID, 256, 0, stream>>>(PA, PB, nA, nB, out);
}